// Round 8
// baseline (564.396 us; speedup 1.0000x reference)
//
#include <hip/hip_runtime.h>
#include <hip/hip_bf16.h>

typedef unsigned short u16;
typedef __attribute__((ext_vector_type(4))) unsigned short u16x4;
typedef __attribute__((ext_vector_type(8))) unsigned short u16x8;
typedef __attribute__((ext_vector_type(8))) short s16x8;
typedef __attribute__((ext_vector_type(4))) float f32x4;

#define HEADS 12
#define NSEQ 1024
#define DIMM 768
#define DHEAD 64

__device__ __forceinline__ float b2f(u16 h) {
  union { unsigned u; float f; } v; v.u = ((unsigned)h) << 16; return v.f;
}
__device__ __forceinline__ u16 f2b(float f) {
  union { float f; unsigned u; } v; v.f = f;
  unsigned r = v.u + 0x7fffu + ((v.u >> 16) & 1u);
  return (u16)(r >> 16);
}
__device__ __forceinline__ void gl_lds16(const u16* g, u16* l) {
  __builtin_amdgcn_global_load_lds(
      (const __attribute__((address_space(1))) void*)g,
      (__attribute__((address_space(3))) void*)l, 16, 0, 0);
}

// --------------------------- double-buffered MFMA accumulate (m97 lineage)
__device__ __forceinline__ void gemm_acc(
    const u16* __restrict__ A, const u16* __restrict__ BT,
    int K, int lda, int ldb, int m0, int n0,
    u16* As, u16* Bs, f32x4 acc[4][4])
{
  const int tid = threadIdx.x;
  const int lane = tid & 63;
  const int wv = tid >> 6;
  const int wm0 = (wv >> 1) * 64;
  const int wn0 = (wv & 1) * 64;
  const int l15 = lane & 15;
  const int quad = lane >> 4;
  const int srow = lane >> 2;
  const int scol = (lane & 3) * 8;

  const u16* Ab = A + (long)(m0 + wv * 32 + srow) * lda + scol;
  const u16* Bb = BT + (long)(n0 + wv * 32 + srow) * ldb + scol;
  u16* AsW = As + (wv * 32) * 32;
  u16* BsW = Bs + (wv * 32) * 32;

  #pragma unroll
  for (int t = 0; t < 2; ++t) {
    gl_lds16(Ab + (long)t * 16 * lda, AsW + t * 16 * 32);
    gl_lds16(Bb + (long)t * 16 * ldb, BsW + t * 16 * 32);
  }

  int cur = 0;
  for (int k0 = 0; k0 < K; k0 += 32) {
    __syncthreads();
    if (k0 + 32 < K) {
      const int nxt = cur ^ 1;
      #pragma unroll
      for (int t = 0; t < 2; ++t) {
        gl_lds16(Ab + (k0 + 32) + (long)t * 16 * lda, AsW + nxt * 4096 + t * 16 * 32);
        gl_lds16(Bb + (k0 + 32) + (long)t * 16 * ldb, BsW + nxt * 4096 + t * 16 * 32);
      }
    }
    const u16* Ac = As + cur * 4096;
    const u16* Bc = Bs + cur * 4096;
    s16x8 af[4], bfr[4];
    #pragma unroll
    for (int i = 0; i < 4; ++i)
      af[i] = *(const s16x8*)&Ac[(wm0 + i * 16 + l15) * 32 + quad * 8];
    #pragma unroll
    for (int j = 0; j < 4; ++j)
      bfr[j] = *(const s16x8*)&Bc[(wn0 + j * 16 + l15) * 32 + quad * 8];
    #pragma unroll
    for (int i = 0; i < 4; ++i)
      #pragma unroll
      for (int j = 0; j < 4; ++j)
        acc[i][j] = __builtin_amdgcn_mfma_f32_16x16x32_bf16(af[i], bfr[j], acc[i][j], 0, 0, 0);
    cur ^= 1;
  }
}

template<bool GELU, bool RESID>
__global__ __launch_bounds__(256)
void gemm_one(const u16* __restrict__ A, const u16* __restrict__ BT,
              const float* __restrict__ bias, const u16* __restrict__ resid,
              const float* __restrict__ rg, const float* __restrict__ rb,
              u16* __restrict__ C, int K, int lda, int ldb, int ldc)
{
  __shared__ u16 As[8192], Bs[8192];
  f32x4 acc[4][4];
  #pragma unroll
  for (int i = 0; i < 4; ++i)
    #pragma unroll
    for (int j = 0; j < 4; ++j)
      acc[i][j] = {0.f, 0.f, 0.f, 0.f};
  const int m0 = blockIdx.x * 128, n0 = blockIdx.y * 128;
  gemm_acc(A, BT, K, lda, ldb, m0, n0, As, Bs, acc);

  const int lane = threadIdx.x & 63;
  const int wv = threadIdx.x >> 6;
  const int wm0 = (wv >> 1) * 64, wn0 = (wv & 1) * 64;
  const int l15 = lane & 15, quad = lane >> 4;
  #pragma unroll
  for (int i = 0; i < 4; ++i)
    #pragma unroll
    for (int j = 0; j < 4; ++j) {
      const int col = n0 + wn0 + j * 16 + l15;
      const float bvv = bias[col];
      #pragma unroll
      for (int v = 0; v < 4; ++v) {
        const int row = m0 + wm0 + i * 16 + quad * 4 + v;
        float val = acc[i][j][v] + bvv;
        if (GELU) val = 0.5f * val * (1.0f + erff(val * 0.70710678118654752440f));
        if (RESID) val += b2f(resid[(long)row * ldc + col]) * rg[col] + rb[col];
        C[(long)row * ldc + col] = f2b(val);
      }
    }
}

// Q / K / V projections in one launch; V blocks write directly in vT layout.
__global__ __launch_bounds__(256)
void gemm_qkv(const u16* __restrict__ nx, const u16* __restrict__ ns,
              const u16* __restrict__ qT, const u16* __restrict__ kvT,
              const float* __restrict__ bqf, const float* __restrict__ bkvf,
              u16* __restrict__ qb, u16* __restrict__ kb, u16* __restrict__ vT)
{
  __shared__ u16 As[8192], Bs[8192];
  const int z = blockIdx.z;
  const int m0 = blockIdx.x * 128;
  const int n0 = blockIdx.y * 128 + ((z == 2) ? 768 : 0);
  const u16* Aptr = (z == 0) ? nx : ns;
  const u16* Bptr = (z == 0) ? qT : kvT;
  f32x4 acc[4][4];
  #pragma unroll
  for (int i = 0; i < 4; ++i)
    #pragma unroll
    for (int j = 0; j < 4; ++j)
      acc[i][j] = {0.f, 0.f, 0.f, 0.f};
  gemm_acc(Aptr, Bptr, 768, 768, 768, m0, n0, As, Bs, acc);

  const int lane = threadIdx.x & 63;
  const int wv = threadIdx.x >> 6;
  const int wm0 = (wv >> 1) * 64, wn0 = (wv & 1) * 64;
  const int l15 = lane & 15, quad = lane >> 4;

  if (z < 2) {
    u16* C = (z == 0) ? qb : kb;
    const float* bias = (z == 0) ? bqf : bkvf;
    #pragma unroll
    for (int i = 0; i < 4; ++i)
      #pragma unroll
      for (int j = 0; j < 4; ++j) {
        const int col = n0 + wn0 + j * 16 + l15;
        const float bvv = bias[col];
        #pragma unroll
        for (int v = 0; v < 4; ++v) {
          const int row = m0 + wm0 + i * 16 + quad * 4 + v;
          C[(long)row * 768 + col] = f2b(acc[i][j][v] + bvv);
        }
      }
  } else {
    // V: write vT[bh][d][n]; lane's 4 acc values are n-consecutive
    const int b = m0 >> 10;
    #pragma unroll
    for (int i = 0; i < 4; ++i)
      #pragma unroll
      for (int j = 0; j < 4; ++j) {
        const int col = (n0 - 768) + wn0 + j * 16 + l15;   // 0..767
        const float bvv = bkvf[768 + col];
        const int row0 = (m0 + wm0 + i * 16 + quad * 4) & 1023;
        u16x4 pk;
        #pragma unroll
        for (int v = 0; v < 4; ++v) pk[v] = f2b(acc[i][j][v] + bvv);
        *(u16x4*)&vT[((long)(b * HEADS + (col >> 6)) * 64 + (col & 63)) * 1024 + row0] = pk;
      }
  }
}

// ------------------------------------------------ fused epipolar attention
__global__ __launch_bounds__(256, 3)
void fattn(const u16* __restrict__ qb, const u16* __restrict__ kb,
           const u16* __restrict__ vT, const u16* __restrict__ wm,
           u16* __restrict__ outA)
{
  __shared__ u16 Qs[2 * 64 * 32];
  __shared__ u16 Ks[2 * 64 * 32];
  __shared__ u16 Vs[2 * 64 * 32];
  __shared__ u16 Ws[64][72];
  __shared__ u16 Ps[64][72];

  const int bh = blockIdx.y;
  const int b = bh / HEADS, h = bh - b * HEADS;
  const int q0 = blockIdx.x * 64;
  const int tid = threadIdx.x;
  const int lane = tid & 63;
  const int wv = tid >> 6;
  const int l15 = lane & 15;
  const int quad = lane >> 4;
  const int srow = lane >> 2;
  const int scol = (lane & 3) * 8;

  const u16* Qg = qb + ((long)b * NSEQ + q0) * DIMM + h * DHEAD;
  const u16* Kg = kb + (long)b * NSEQ * DIMM + h * DHEAD;
  const u16* Vg = vT + (long)bh * DHEAD * NSEQ;
  const u16* Wg = wm + ((long)b * NSEQ + q0) * NSEQ;

  #pragma unroll
  for (int h2 = 0; h2 < 2; ++h2)
    gl_lds16(Qg + (long)(wv * 16 + srow) * DIMM + h2 * 32 + scol,
             Qs + (h2 * 64 + wv * 16) * 32);

  f32x4 Sacc[4], Oacc[4];
  float mrow[4], lrow[4];
  #pragma unroll
  for (int j = 0; j < 4; ++j) {
    Oacc[j] = {0.f, 0.f, 0.f, 0.f};
    mrow[j] = -3.0e38f;
    lrow[j] = 0.f;
  }
  s16x8 qf[2];

  for (int kt = 0; kt < 16; ++kt) {
    __syncthreads();
    #pragma unroll
    for (int h2 = 0; h2 < 2; ++h2) {
      gl_lds16(Kg + (long)(kt * 64 + wv * 16 + srow) * DIMM + h2 * 32 + scol,
               Ks + (h2 * 64 + wv * 16) * 32);
      gl_lds16(Vg + (long)(wv * 16 + srow) * NSEQ + kt * 64 + h2 * 32 + scol,
               Vs + (h2 * 64 + wv * 16) * 32);
    }
    #pragma unroll
    for (int t = 0; t < 2; ++t) {
      const int col = (lane & 3) * 16 + t * 8;
      u16x8 wvv = *(const u16x8*)&Wg[(long)(wv * 16 + srow) * NSEQ + kt * 64 + col];
      *(u16x8*)&Ws[wv * 16 + srow][col] = wvv;
    }
    __syncthreads();

    if (kt == 0) {
      qf[0] = *(const s16x8*)&Qs[(0 * 64 + wv * 16 + l15) * 32 + quad * 8];
      qf[1] = *(const s16x8*)&Qs[(1 * 64 + wv * 16 + l15) * 32 + quad * 8];
    }

    #pragma unroll
    for (int j = 0; j < 4; ++j) Sacc[j] = {0.f, 0.f, 0.f, 0.f};
    #pragma unroll
    for (int j = 0; j < 4; ++j)
      #pragma unroll
      for (int h2 = 0; h2 < 2; ++h2) {
        s16x8 kf = *(const s16x8*)&Ks[(h2 * 64 + j * 16 + l15) * 32 + quad * 8];
        Sacc[j] = __builtin_amdgcn_mfma_f32_16x16x32_bf16(qf[h2], kf, Sacc[j], 0, 0, 0);
      }

    #pragma unroll
    for (int j = 0; j < 4; ++j)
      #pragma unroll
      for (int v = 0; v < 4; ++v)
        Sacc[j][v] *= b2f(Ws[wv * 16 + quad * 4 + v][j * 16 + l15]);
    #pragma unroll
    for (int v = 0; v < 4; ++v) {
      float tm = fmaxf(fmaxf(Sacc[0][v], Sacc[1][v]), fmaxf(Sacc[2][v], Sacc[3][v]));
      tm = fmaxf(tm, __shfl_xor(tm, 1));
      tm = fmaxf(tm, __shfl_xor(tm, 2));
      tm = fmaxf(tm, __shfl_xor(tm, 4));
      tm = fmaxf(tm, __shfl_xor(tm, 8));
      const float mnew = fmaxf(mrow[v], tm);
      const float al = __expf(mrow[v] - mnew);
      float rs = 0.f;
      #pragma unroll
      for (int j = 0; j < 4; ++j) {
        const float e = __expf(Sacc[j][v] - mnew);
        Sacc[j][v] = e;
        rs += e;
      }
      rs += __shfl_xor(rs, 1);
      rs += __shfl_xor(rs, 2);
      rs += __shfl_xor(rs, 4);
      rs += __shfl_xor(rs, 8);
      lrow[v] = lrow[v] * al + rs;
      mrow[v] = mnew;
      #pragma unroll
      for (int jn = 0; jn < 4; ++jn) Oacc[jn][v] *= al;
    }
    #pragma unroll
    for (int j = 0; j < 4; ++j)
      #pragma unroll
      for (int v = 0; v < 4; ++v)
        Ps[wv * 16 + quad * 4 + v][j * 16 + l15] = f2b(Sacc[j][v]);

    #pragma unroll
    for (int h2 = 0; h2 < 2; ++h2) {
      s16x8 af = *(const s16x8*)&Ps[wv * 16 + l15][h2 * 32 + quad * 8];
      #pragma unroll
      for (int jn = 0; jn < 4; ++jn) {
        s16x8 vf = *(const s16x8*)&Vs[(h2 * 64 + jn * 16 + l15) * 32 + quad * 8];
        Oacc[jn] = __builtin_amdgcn_mfma_f32_16x16x32_bf16(af, vf, Oacc[jn], 0, 0, 0);
      }
    }
  }

  #pragma unroll
  for (int v = 0; v < 4; ++v) {
    const int row = q0 + wv * 16 + quad * 4 + v;
    const float inv = 1.0f / lrow[v];
    #pragma unroll
    for (int jn = 0; jn < 4; ++jn)
      outA[((long)(b * NSEQ + row)) * DIMM + h * DHEAD + jn * 16 + l15] =
          f2b(Oacc[jn][v] * inv);
  }
}

// ------------------- pure row-norms for x and src in one launch (grid 8192)
__global__ __launch_bounds__(256)
void norm_xs(const float* __restrict__ x, const float* __restrict__ src,
             u16* __restrict__ ox, u16* __restrict__ osrc)
{
  const int which = blockIdx.x >> 12;
  const long row = blockIdx.x & 4095;
  const float* in = (which ? src : x) + row * DIMM;
  u16* out = (which ? osrc : ox) + row * DIMM;
  const int tid = threadIdx.x;
  __shared__ float s1[8], s2[8];
  float v0 = in[tid], v1 = in[tid + 256], v2 = in[tid + 512];
  float s = v0 + v1 + v2;
  #pragma unroll
  for (int off = 32; off; off >>= 1) s += __shfl_down(s, off);
  const int lane = tid & 63, wid = tid >> 6;
  if (!lane) s1[wid] = s;
  __syncthreads();
  if (!tid) s1[4] = s1[0] + s1[1] + s1[2] + s1[3];
  __syncthreads();
  const float mu = s1[4] / 768.0f;
  float d0 = v0 - mu, d1 = v1 - mu, d2 = v2 - mu;
  float sq = d0 * d0 + d1 * d1 + d2 * d2;
  #pragma unroll
  for (int off = 32; off; off >>= 1) sq += __shfl_down(sq, off);
  if (!lane) s2[wid] = sq;
  __syncthreads();
  if (!tid) s2[4] = s2[0] + s2[1] + s2[2] + s2[3];
  __syncthreads();
  const float rstd = 1.0f / sqrtf(s2[4] / 768.0f + 1e-5f);
  out[tid]       = f2b(d0 * rstd);
  out[tid + 256] = f2b(d1 * rstd);
  out[tid + 512] = f2b(d2 * rstd);
}

// ---------------------------------------- bf16-in norm (pure, no affine)
__global__ __launch_bounds__(256)
void norm_b(const u16* __restrict__ in, u16* __restrict__ out)
{
  const long base = (long)blockIdx.x * DIMM;
  const int tid = threadIdx.x;
  __shared__ float s1[8], s2[8];
  const u16* p = in + base;
  float v0 = b2f(p[tid]), v1 = b2f(p[tid + 256]), v2 = b2f(p[tid + 512]);
  float s = v0 + v1 + v2;
  #pragma unroll
  for (int off = 32; off; off >>= 1) s += __shfl_down(s, off);
  const int lane = tid & 63, wid = tid >> 6;
  if (!lane) s1[wid] = s;
  __syncthreads();
  if (!tid) s1[4] = s1[0] + s1[1] + s1[2] + s1[3];
  __syncthreads();
  const float mu = s1[4] / 768.0f;
  float d0 = v0 - mu, d1 = v1 - mu, d2 = v2 - mu;
  float sq = d0 * d0 + d1 * d1 + d2 * d2;
  #pragma unroll
  for (int off = 32; off; off >>= 1) sq += __shfl_down(sq, off);
  if (!lane) s2[wid] = sq;
  __syncthreads();
  if (!tid) s2[4] = s2[0] + s2[1] + s2[2] + s2[3];
  __syncthreads();
  const float rstd = 1.0f / sqrtf(s2[4] / 768.0f + 1e-5f);
  u16* o = out + base;
  o[tid]       = f2b(d0 * rstd);
  o[tid + 256] = f2b(d1 * rstd);
  o[tid + 512] = f2b(d2 * rstd);
}

// ---------------------------------------- final affine LN: bf16 in, f32 out
__global__ __launch_bounds__(256)
void ln_final(const u16* __restrict__ in, const float* __restrict__ g,
              const float* __restrict__ bb, float* __restrict__ out)
{
  const long base = (long)blockIdx.x * DIMM;
  const int tid = threadIdx.x;
  __shared__ float s1[8], s2[8];
  const u16* p = in + base;
  float v0 = b2f(p[tid]), v1 = b2f(p[tid + 256]), v2 = b2f(p[tid + 512]);
  float s = v0 + v1 + v2;
  #pragma unroll
  for (int off = 32; off; off >>= 1) s += __shfl_down(s, off);
  const int lane = tid & 63, wid = tid >> 6;
  if (!lane) s1[wid] = s;
  __syncthreads();
  if (!tid) s1[4] = s1[0] + s1[1] + s1[2] + s1[3];
  __syncthreads();
  const float mu = s1[4] / 768.0f;
  float d0 = v0 - mu, d1 = v1 - mu, d2 = v2 - mu;
  float sq = d0 * d0 + d1 * d1 + d2 * d2;
  #pragma unroll
  for (int off = 32; off; off >>= 1) sq += __shfl_down(sq, off);
  if (!lane) s2[wid] = sq;
  __syncthreads();
  if (!tid) s2[4] = s2[0] + s2[1] + s2[2] + s2[3];
  __syncthreads();
  const float rstd = 1.0f / sqrtf(s2[4] / 768.0f + 1e-5f);
  float* o = out + base;
  o[tid]       = d0 * rstd * g[tid]       + bb[tid];
  o[tid + 256] = d1 * rstd * g[tid + 256] + bb[tid + 256];
  o[tid + 512] = d2 * rstd * g[tid + 512] + bb[tid + 512];
}

// ---------- weight transposes (LN-gain folded) + bias folds in ONE launch
__global__ __launch_bounds__(256)
void trans_bias(const float* w0, const float* w1, const float* w2,
                const float* w3, const float* w4, const float* w5,
                const float* gq, const float* gk, const float* gv, const float* gp,
                const float* bq, const float* bk, const float* bv, const float* b1,
                const float* lnqb, const float* lnkb, const float* lnvb, const float* preb,
                u16* d0, u16* d12, u16* d3, u16* d4, u16* d5,
                float* obq, float* obkv, float* ob1)
{
  const int zz = blockIdx.z;
  if (zz == 6) {
    // bias folds: b' = (b_w + b_ln @ W) * scale
    const int y = blockIdx.y;
    if (y >= 4) return;
    const int c = blockIdx.x * 256 + threadIdx.x;
    const float* W; const float* bln; const float* bw; float* out;
    int C; float sc = 1.0f;
    switch (y) {
      case 0: W = w0; bln = lnqb; bw = bq; out = obq;        C = 768;  sc = 0.125f; break;
      case 1: W = w1; bln = lnkb; bw = bk; out = obkv;       C = 768;  break;
      case 2: W = w2; bln = lnvb; bw = bv; out = obkv + 768; C = 768;  break;
      default: W = w4; bln = preb; bw = b1; out = ob1;       C = 1536; break;
    }
    if (c >= C) return;
    float s = bw[c];
    for (int r = 0; r < 768; ++r) s += bln[r] * W[(long)r * C + c];
    out[c] = s * sc;
    return;
  }
  const float* src; const float* g; u16* dst; int R, C; float sc = 1.0f;
  switch (zz) {
    case 0: src = w0; g = gq; dst = d0;  R = 768;  C = 768;  sc = 0.125f; break;
    case 1: src = w1; g = gk; dst = d12; R = 768;  C = 768;  break;
    case 2: src = w2; g = gv; dst = d12 + 768 * 768; R = 768; C = 768; break;
    case 3: src = w3; g = nullptr; dst = d3; R = 768;  C = 768;  break;
    case 4: src = w4; g = gp; dst = d4; R = 768;  C = 1536; break;
    default: src = w5; g = nullptr; dst = d5; R = 1536; C = 768; break;
  }
  const int c0 = blockIdx.x * 32;
  const int r0 = blockIdx.y * 32;
  if (c0 >= C || r0 >= R) return;
  __shared__ u16 t[32][36];
  const int tid = threadIdx.x;
  const int i = tid >> 3;
  const int j4 = (tid & 7) * 4;
  const float rs = (g ? g[r0 + i] : 1.0f) * sc;
  #pragma unroll
  for (int jj = 0; jj < 4; ++jj)
    t[i][j4 + jj] = f2b(src[(long)(r0 + i) * C + c0 + j4 + jj] * rs);
  __syncthreads();
  u16x4 ov;
  #pragma unroll
  for (int jj = 0; jj < 4; ++jj) ov[jj] = t[j4 + jj][i];
  *(u16x4*)&dst[(long)(c0 + i) * R + r0 + j4] = ov;
}

// --------------- epipolar dw rows (camera setup computed per block inline)
__global__ __launch_bounds__(256)
void epi_dw(const float* __restrict__ intr, const float* __restrict__ c2w,
            float* __restrict__ dw)
{
  const int rowid = blockIdx.x;          // db*1024 + n
  const int db = rowid >> 10;
  const int n = rowid & 1023;
  const int d = db >> 2, b = db & 3;
  __shared__ float S[36];
  if (threadIdx.x == 0) {
    const int sidx = (d == 0) ? 1 : 0;
    const int tidx = 1 - sidx;
    float k3[9], sr[9], st[3], tr[9], tt[3];
    const float Wf = 32.0f * 16.0f / 9.0f;
    for (int j = 0; j < 3; ++j) {
      k3[j]     = intr[(b * 4 + 0) * 4 + j] * Wf;
      k3[3 + j] = intr[(b * 4 + 1) * 4 + j] * 32.0f;
      k3[6 + j] = intr[(b * 4 + 2) * 4 + j];
    }
    k3[2] = 16.0f; k3[5] = 16.0f;
    for (int i = 0; i < 3; ++i) {
      for (int j = 0; j < 3; ++j) {
        sr[i * 3 + j] = c2w[((sidx * 4 + b) * 4 + i) * 4 + j];
        tr[i * 3 + j] = c2w[((tidx * 4 + b) * 4 + i) * 4 + j];
      }
      st[i] = c2w[((sidx * 4 + b) * 4 + i) * 4 + 3];
      tt[i] = c2w[((tidx * 4 + b) * 4 + i) * 4 + 3];
    }
    double a = tr[0], bb_ = tr[1], c = tr[2];
    double dd2 = tr[3], e = tr[4], f = tr[5];
    double g2 = tr[6], h2 = tr[7], i2 = tr[8];
    double det = a * (e * i2 - f * h2) - bb_ * (dd2 * i2 - f * g2) + c * (dd2 * h2 - e * g2);
    double inv[9] = {
      (e * i2 - f * h2), (c * h2 - bb_ * i2), (bb_ * f - c * e),
      (f * g2 - dd2 * i2), (a * i2 - c * g2), (c * dd2 - a * f),
      (dd2 * h2 - e * g2), (bb_ * g2 - a * h2), (a * e - bb_ * dd2)
    };
    float tri[9];
    for (int t2 = 0; t2 < 9; ++t2) tri[t2] = (float)(inv[t2] / det);
    float o2[3], oij[3];
    for (int i3 = 0; i3 < 3; ++i3)
      o2[i3] = tri[i3 * 3] * st[0] + tri[i3 * 3 + 1] * st[1] + tri[i3 * 3 + 2] * st[2] - tt[i3];
    for (int i3 = 0; i3 < 3; ++i3)
      oij[i3] = k3[i3 * 3] * o2[0] + k3[i3 * 3 + 1] * o2[1] + k3[i3 * 3 + 2] * o2[2];
    const float ozf = oij[2];
    oij[0] = oij[0] / ozf; oij[1] = oij[1] / ozf; oij[2] = ozf / ozf;
    for (int t2 = 0; t2 < 9; ++t2) { S[t2] = k3[t2]; S[9 + t2] = sr[t2]; S[21 + t2] = tri[t2]; }
    for (int t2 = 0; t2 < 3; ++t2) { S[18 + t2] = st[t2]; S[30 + t2] = tt[t2]; S[33 + t2] = oij[t2]; }
  }
  __syncthreads();

  // U for pixel n (redundant per thread; same op order as before)
  const float ncx = ((float)(n & 31) - S[2]) / S[0];
  const float ncy = ((float)(n >> 5) - S[5]) / S[4];
  const float p0 = S[9]  * ncx + S[10] * ncy + S[11] + S[18];
  const float p1 = S[12] * ncx + S[13] * ncy + S[14] + S[19];
  const float p2 = S[15] * ncx + S[16] * ncy + S[17] + S[20];
  const float q0 = S[21] * p0 + S[22] * p1 + S[23] * p2 - S[30];
  const float q1 = S[24] * p0 + S[25] * p1 + S[26] * p2 - S[31];
  const float q2 = S[27] * p0 + S[28] * p1 + S[29] * p2 - S[32];
  const float w0 = S[0] * q0 + S[1] * q1 + S[2] * q2;
  const float w1 = S[3] * q0 + S[4] * q1 + S[5] * q2;
  const float w2 = S[6] * q0 + S[7] * q1 + S[8] * q2;
  const float pz = w2 + 1e-6f;
  const float Ux = w0 / pz - S[33];
  const float Uy = w1 / pz - S[34];
  const float Uz = w2 / pz - S[35];
  const float vlen = sqrtf(Ux * Ux + Uy * Uy + Uz * Uz);
  const float ox = S[33], oy = S[34], oz = S[35];

  const int tid = threadIdx.x;
  __shared__ float red[8];
  float vals[4];
  float mx = -1e30f;
  #pragma unroll
  for (int i = 0; i < 4; ++i) {
    const int m = tid + i * 256;
    const float cx = (float)(m & 31) - ox;
    const float cy = (float)(m >> 5) - oy;
    const float cz = 1.0f - oz;
    const float crx = Uy * cz - Uz * cy;
    const float cry = Uz * cx - Ux * cz;
    const float crz = Ux * cy - Uy * cx;
    const float area = sqrtf(crx * crx + cry * cry + crz * crz);
    const float dist = area / vlen;
    const float t = 50.0f * (dist - 0.5f);
    const float dwv = 1.0f - 1.0f / (1.0f + __expf(-t));
    vals[i] = dwv;
    mx = fmaxf(mx, dwv);
  }
  #pragma unroll
  for (int off = 32; off; off >>= 1) mx = fmaxf(mx, __shfl_down(mx, off));
  const int lane = tid & 63, wid = tid >> 6;
  if (!lane) red[wid] = mx;
  __syncthreads();
  if (!tid) red[4] = fmaxf(fmaxf(red[0], red[1]), fmaxf(red[2], red[3]));
  __syncthreads();
  const bool fill1 = red[4] < 0.5f;
  float* out = dw + (long)rowid * 1024;
  #pragma unroll
  for (int i = 0; i < 4; ++i)
    out[tid + i * 256] = fill1 ? 1.0f : vals[i];
}

// --------- wmap: bf16 map for fattn + f32 wm_full output (fused broadcast)
__global__ __launch_bounds__(256)
void epi_wmap(const float* __restrict__ dw, u16* __restrict__ wm,
              float* __restrict__ wm_full)
{
  __shared__ float tb[32][33];
  const int b = blockIdx.z;
  const int q0 = blockIdx.x * 32;
  const int k0 = blockIdx.y * 32;
  const int tid = threadIdx.x;
  const int i = tid >> 3;
  const int j4 = (tid & 7) * 4;
  const float* d1 = dw + ((long)(4 + b) * 1024 + (k0 + i)) * 1024 + q0 + j4;
  #pragma unroll
  for (int jj = 0; jj < 4; ++jj) tb[i][j4 + jj] = d1[jj];
  __syncthreads();
  const float* d0 = dw + ((long)b * 1024 + (q0 + i)) * 1024 + k0 + j4;
  u16x4 pk;
  f32x4 wf;
  #pragma unroll
  for (int jj = 0; jj < 4; ++jj) {
    const float w = d0[jj] * tb[j4 + jj][i];
    wf[jj] = w;
    pk[jj] = f2b(w);
  }
  *(u16x4*)&wm[((long)b * 1024 + q0 + i) * 1024 + k0 + j4] = pk;
  #pragma unroll
  for (int h = 0; h < HEADS; ++h)
    *(f32x4*)&wm_full[((long)(b * HEADS + h) * 1024 + q0 + i) * 1024 + k0 + j4] = wf;
}

// ---------------------------------------------------------------------------
extern "C" void kernel_launch(void* const* d_in, const int* in_sizes, int n_in,
                              void* d_out, int out_size, void* d_ws, size_t ws_size,
                              hipStream_t stream)
{
  (void)in_sizes; (void)n_in; (void)out_size; (void)ws_size;
  const float* x     = (const float*)d_in[0];
  const float* src   = (const float*)d_in[1];
  const float* intr  = (const float*)d_in[2];
  const float* c2w   = (const float*)d_in[3];
  const float* lnq_g = (const float*)d_in[4];
  const float* lnq_b = (const float*)d_in[5];
  const float* Wq    = (const float*)d_in[6];
  const float* bq    = (const float*)d_in[7];
  const float* lnk_g = (const float*)d_in[8];
  const float* lnk_b = (const float*)d_in[9];
  const float* Wk    = (const float*)d_in[10];
  const float* bk    = (const float*)d_in[11];
  const float* lnv_g = (const float*)d_in[12];
  const float* lnv_b = (const float*)d_in[13];
  const float* Wv    = (const float*)d_in[14];
  const float* bv    = (const float*)d_in[15];
  const float* Wp    = (const float*)d_in[16];
  const float* bp    = (const float*)d_in[17];
  const float* pre_g = (const float*)d_in[18];
  const float* pre_b = (const float*)d_in[19];
  const float* W1    = (const float*)d_in[20];
  const float* b1    = (const float*)d_in[21];
  const float* W2    = (const float*)d_in[22];
  const float* b2    = (const float*)d_in[23];
  const float* post_g= (const float*)d_in[24];
  const float* post_b= (const float*)d_in[25];

  char* ws = (char*)d_ws;
  size_t off = 0;
  auto alloc = [&](size_t bytes) -> char* {
    char* p = ws + off;
    off = (off + bytes + 255) & ~(size_t)255;
    return p;
  };
  const size_t SEQD = (size_t)4096 * 768 * 2;

  u16* WqT  = (u16*)alloc(768 * 768 * 2);
  u16* WkvT = (u16*)alloc((size_t)1536 * 768 * 2);
  u16* WpT  = (u16*)alloc(768 * 768 * 2);
  u16* W1T  = (u16*)alloc(768 * 1536 * 2);
  u16* W2T  = (u16*)alloc(1536 * 768 * 2);
  float* bqf  = (float*)alloc(768 * 4);
  float* bkvf = (float*)alloc(1536 * 4);
  float* b1f  = (float*)alloc(1536 * 4);
  char* pool = alloc(6 * SEQD);
  u16* wmapb  = (u16*)alloc((size_t)4 * 1024 * 1024 * 2);
  float* dwbuf = (float*)alloc((size_t)8 * 1024 * 1024 * 4);

  u16* S0 = (u16*)pool;                 // norm(x) -> a
  u16* S1 = (u16*)(pool + SEQD);        // norm(src) -> t0
  u16* S2 = (u16*)(pool + 2 * SEQD);    // q -> z_pure
  u16* S3 = (u16*)(pool + 3 * SEQD);    // kb -> h (S3+S4)
  u16* S4 = (u16*)(pool + 4 * SEQD);    // vT -> h upper
  u16* S5 = (u16*)(pool + 5 * SEQD);    // t1

  float* out_z  = (float*)d_out;
  float* out_wm = (float*)d_out + (size_t)4 * 1024 * 768;

  // 1. weight transposes + bias folds
  trans_bias<<<dim3(48, 48, 7), 256, 0, stream>>>(
      Wq, Wk, Wv, Wp, W1, W2, lnq_g, lnk_g, lnv_g, pre_g,
      bq, bk, bv, b1, lnq_b, lnk_b, lnv_b, pre_b,
      WqT, WkvT, WpT, W1T, W2T, bqf, bkvf, b1f);

  // 2-3. epipolar weights
  epi_dw<<<8192, 256, 0, stream>>>(intr, c2w, dwbuf);
  epi_wmap<<<dim3(32, 32, 4), 256, 0, stream>>>(dwbuf, wmapb, out_wm);

  // 4. pure norms of x and src
  norm_xs<<<8192, 256, 0, stream>>>(x, src, S0, S1);

  // 5. Q/K/V projections; V written directly as vT
  gemm_qkv<<<dim3(32, 6, 3), 256, 0, stream>>>(
      S0, S1, WqT, WkvT, bqf, bkvf, S2, S3, S4);

  // 6. fused attention -> a (S0)
  fattn<<<dim3(16, 48), 256, 0, stream>>>(S2, S3, S4, wmapb, S0);

  // 7. proj: t0 (S1) = a @ Wp + bp
  gemm_one<false, false><<<dim3(32, 6), 256, 0, stream>>>(
      S0, WpT, bp, nullptr, nullptr, nullptr, S1, 768, 768, 768, 768);

  // 8. z_pure (S2) = norm(t0)
  norm_b<<<4096, 256, 0, stream>>>(S1, S2);

  // 9. h (S3+S4) = gelu(z_pure @ W1' + b1')
  gemm_one<true, false><<<dim3(32, 12), 256, 0, stream>>>(
      S2, W1T, b1f, nullptr, nullptr, nullptr, S3, 768, 768, 768, 1536);

  // 10. t1 (S5) = (z_pure*pre_g + pre_b) + (h @ W2 + b2)
  gemm_one<false, true><<<dim3(32, 6), 256, 0, stream>>>(
      S3, W2T, b2, S2, pre_g, pre_b, S5, 1536, 1536, 1536, 768);

  // 11. out_z = LN(t1), f32
  ln_final<<<4096, 256, 0, stream>>>(S5, post_g, post_b, out_z);
}